// Round 2
// 706.628 us; speedup vs baseline: 1.0067x; 1.0067x over previous
//
#include <hip/hip_runtime.h>
#include <hip/hip_bf16.h>
#include <math.h>

// N=200000 nodes, U=100000 users, D=64, L=3, E=3,000,000 per edge list, NLINK=100000.
// ws (wide mode): 4 bf16 node bufs (102.4MB) + 2 bin/col (24MB, sorted in place) + aux ~= 130MB.
// Falls back to the 3-buffer sequential schedule if ws_size is too small.
//
// Key idea this revision: after each mix, s-chain and t-chain USER rows are bit-identical.
// Redirect t-chain user gathers to the s-chain buffer and merge the two per-layer agg
// dispatches so the shared 12.8MB user region is co-accessed (D5-style cache sharing).

typedef unsigned short u16;
typedef unsigned int   u32;
typedef __attribute__((ext_vector_type(8))) short bf16x8;
typedef __attribute__((ext_vector_type(4))) float f32x4;

#define BSHIFT 8                 // 256 nodes per coarse bucket
#define NODESB 256               // nodes per bucket
#define NBPAD  1024              // padded bucket-count array (782 used)
#define BCAP   4096              // LDS staging per sort bucket (mean ~3840)
#define OVF    8                 // +2048 entries of per-thread register headroom
#define HCHUNK 8192              // edges per hist block
#define BCHUNK 8192              // edges per bin block (LDS presort)

__device__ __forceinline__ float bf2f(u16 v) {
    u32 x = ((u32)v) << 16;
    return __builtin_bit_cast(float, x);
}
__device__ __forceinline__ u16 f2bf(float f) {
    u32 x = __builtin_bit_cast(u32, f);
    u32 r = x + 0x7fffu + ((x >> 16) & 1u);   // round-to-nearest-even
    return (u16)(r >> 16);
}
__device__ __forceinline__ u32 pack2(float a, float b) {
    return (u32)f2bf(a) | ((u32)f2bf(b) << 16);
}
__device__ __forceinline__ float flo(u32 p) { return __builtin_bit_cast(float, p << 16); }
__device__ __forceinline__ float fhi(u32 p) { return __builtin_bit_cast(float, p & 0xffff0000u); }
__device__ __forceinline__ int imin(int a, int b) { return a < b ? a : b; }

// ---- D1: fused hist(s) + hist(t) + W->bf16 prep + emb->bf16 staging ----
__global__ __launch_bounds__(256) void prep_hist(const int* __restrict__ sdst,
        const int* __restrict__ tdst, int e, int* __restrict__ gcnt2,
        const float* __restrict__ mw, u16* __restrict__ mwb,
        const float* __restrict__ emb, u32* __restrict__ embb, int nelem,
        int nhist, int nwprep) {
    __shared__ int lcnt[NBPAD];
    int bid = blockIdx.x, tid = threadIdx.x;
    if (bid < 2 * nhist) {
        const int* dst = (bid < nhist) ? sdst : tdst;
        int* gcnt = gcnt2 + ((bid < nhist) ? 0 : NBPAD);
        int cb = (bid < nhist) ? bid : bid - nhist;
        for (int i = tid; i < NBPAD; i += 256) lcnt[i] = 0;
        __syncthreads();
        int base = cb * HCHUNK, end = imin(base + HCHUNK, e);
        for (int i = base + tid; i < end; i += 256)
            atomicAdd(&lcnt[(u32)dst[i] >> BSHIFT], 1);
        __syncthreads();
        for (int i = tid; i < NBPAD; i += 256)
            if (lcnt[i]) atomicAdd(&gcnt[i], lcnt[i]);
    } else if (bid < 2 * nhist + nwprep) {
        int idx = (bid - 2 * nhist) * 256 + tid;
        if (idx < 3 * 64 * 128) mwb[idx] = f2bf(mw[idx]);
    } else {
        int idx = (bid - 2 * nhist - nwprep) * 1024 + tid * 4;   // 4 floats / thread
        if (idx < nelem) {
            float4 v = *(const float4*)(emb + idx);
            uint2 r;
            r.x = pack2(v.x, v.y);
            r.y = pack2(v.z, v.w);
            *(uint2*)(embb + (idx >> 1)) = r;
        }
    }
}

// ---- D2: parallel bucket scans (2 blocks, 1024 counts @ 4/thread) + pred0 ----
__global__ __launch_bounds__(256) void scan_pred0(const int* __restrict__ gcnt2, int nb,
        int* __restrict__ bbase_s, int* __restrict__ bbase_t, int* __restrict__ cur2,
        int* __restrict__ rs_s, int* __restrict__ rs_t, int n,
        const float* __restrict__ emb, const int* __restrict__ l0, const int* __restrict__ l1,
        const float* __restrict__ pw, float* __restrict__ acc, int nl) {
    int bid = blockIdx.x;
    int tid = threadIdx.x;
    if (bid < 2) {
        __shared__ int part[256];
        const int* g = gcnt2 + bid * NBPAD;
        int* bb = bid ? bbase_t : bbase_s;
        int* cu = cur2 + bid * NBPAD;
        int* rs = bid ? rs_t : rs_s;
        int i0 = tid * 4;
        int c[4]; int s = 0;
#pragma unroll
        for (int j = 0; j < 4; ++j) { c[j] = g[i0 + j]; s += c[j]; }  // zero beyond nb
        part[tid] = s;
        __syncthreads();
        for (int off = 1; off < 256; off <<= 1) {
            int t = (tid >= off) ? part[tid - off] : 0;
            __syncthreads();
            part[tid] += t;
            __syncthreads();
        }
        int excl = part[tid] - s;
#pragma unroll
        for (int j = 0; j < 4; ++j) {
            int idx = i0 + j;
            if (idx <= nb) bb[idx] = excl;
            if (idx < nb)  cu[idx] = excl;
            excl += c[j];
        }
        if (tid == 255) rs[n] = part[255];
        return;
    }
    int li = (bid - 2) * 4 + (tid >> 6);
    if (li >= nl) return;
    li = __builtin_amdgcn_readfirstlane(li);
    int lane = tid & 63;
    int u = l0[li], v = l1[li];
    float s = pw[lane] * emb[(size_t)u * 64 + lane] + pw[256 + lane] * emb[(size_t)v * 64 + lane];
#pragma unroll
    for (int off = 32; off > 0; off >>= 1) s += __shfl_xor(s, off, 64);
    if (lane == 0) acc[li] = s;
}

// ---- D3: binning via block-local LDS presort + coalesced segment flush ----
__global__ __launch_bounds__(256) void bin3_kernel(const int* __restrict__ ssrc,
        const int* __restrict__ sdst, const int* __restrict__ tsrc, const int* __restrict__ tdst,
        int e, int* __restrict__ cur2, u32* __restrict__ bin_s, u32* __restrict__ bin_t,
        int nbin) {
    __shared__ u32 stage[BCHUNK];       // 32KB bucket-sorted staging
    __shared__ int lcnt[NBPAD];         // hist -> scatter cursor
    __shared__ int lofs[NBPAD];         // bucket start within stage
    __shared__ int lbase[NBPAD];        // reserved global base
    __shared__ int part[256];
    int bid = blockIdx.x, tid = threadIdx.x;
    const int* src; const int* dst; int* cursor; u32* bin; int cb;
    if (bid < nbin) { src = ssrc; dst = sdst; cursor = cur2; bin = bin_s; cb = bid; }
    else { src = tsrc; dst = tdst; cursor = cur2 + NBPAD; bin = bin_t; cb = bid - nbin; }
    for (int i = tid; i < NBPAD; i += 256) lcnt[i] = 0;
    __syncthreads();
    int base = cb * BCHUNK, end = imin(base + BCHUNK, e);
    // A: histogram chunk by bucket
    for (int i = base + tid; i < end; i += 256)
        atomicAdd(&lcnt[(u32)dst[i] >> BSHIFT], 1);
    __syncthreads();
    // B: block scan -> lofs; bulk global reservation -> lbase; cursor := lofs
    {
        int i0 = tid * 4;
        int c[4]; int s = 0;
#pragma unroll
        for (int j = 0; j < 4; ++j) { c[j] = lcnt[i0 + j]; s += c[j]; }
        part[tid] = s;
        __syncthreads();
        for (int off = 1; off < 256; off <<= 1) {
            int t = (tid >= off) ? part[tid - off] : 0;
            __syncthreads();
            part[tid] += t;
            __syncthreads();
        }
        int excl = part[tid] - s;
#pragma unroll
        for (int j = 0; j < 4; ++j) {
            int idx = i0 + j;
            lofs[idx]  = excl;
            lbase[idx] = c[j] ? atomicAdd(&cursor[idx], c[j]) : 0;
            lcnt[idx]  = excl;          // scatter cursor starts at bucket start
            excl += c[j];
        }
    }
    __syncthreads();
    // C: scatter entries into LDS staging, bucket-sorted
    for (int i = base + tid; i < end; i += 256) {
        int d = dst[i];
        int b = (u32)d >> BSHIFT;
        int p = atomicAdd(&lcnt[b], 1);
        stage[p] = (u32)src[i] | ((u32)(d & (NODESB - 1)) << 18);   // src < 2^18
    }
    __syncthreads();
    // D: flush segments, 4 lanes per bucket -> contiguous burst writes
    for (int bb = tid >> 2; bb < NBPAD; bb += 64) {
        int lo = lofs[bb];
        int cnt = lcnt[bb] - lo;
        int gb = lbase[bb];
        for (int j = tid & 3; j < cnt; j += 4)
            bin[gb + j] = stage[lo + j];
    }
}

// ---- D4: fused per-bucket counting sort (both lists), in place ----
__global__ __launch_bounds__(256) void sort2_kernel(u32* __restrict__ bin_s, u32* __restrict__ bin_t,
        const int* __restrict__ bbase_s, const int* __restrict__ bbase_t,
        int* __restrict__ rs_s, int* __restrict__ rs_t, int n, int nb) {
    __shared__ u32 ent[BCAP];
    __shared__ int cnt[NODESB];
    __shared__ int part[256];
    int bid = blockIdx.x, tid = threadIdx.x;
    u32* bin; const int* bbase; int* rowstart; int b;
    if (bid < nb) { bin = bin_s; bbase = bbase_s; rowstart = rs_s; b = bid; }
    else { bin = bin_t; bbase = bbase_t; rowstart = rs_t; b = bid - nb; }
    int beg = bbase[b], end = bbase[b + 1];
    int sz = end - beg;
    cnt[tid] = 0;
    __syncthreads();
    u32 ovf[OVF];
    for (int i = tid; i < sz; i += 256) {
        u32 v = bin[beg + i];
        if (i < BCAP) ent[i] = v;
        else { int k = (i - BCAP) >> 8; if (k < OVF) ovf[k] = v; }
        atomicAdd(&cnt[v >> 18], 1);
    }
    __syncthreads();
    int c = cnt[tid];
    part[tid] = c;
    __syncthreads();
    for (int off = 1; off < 256; off <<= 1) {
        int t = (tid >= off) ? part[tid - off] : 0;
        __syncthreads();
        part[tid] += t;
        __syncthreads();
    }
    int excl = part[tid] - c;
    int node = (b << BSHIFT) + tid;
    if (node < n) rowstart[node] = beg + excl;
    cnt[tid] = excl;             // running cursor for scatter phase
    __syncthreads();
    for (int i = tid; i < sz; i += 256) {
        u32 v;
        if (i < BCAP) v = ent[i];
        else { int k = (i - BCAP) >> 8; v = (k < OVF) ? ovf[k] : bin[beg + i]; }
        int pos = atomicAdd(&cnt[v >> 18], 1);
        bin[beg + pos] = v & 0x3FFFFu;
    }
}

// ---- mean aggregation (bf16 in/out) + optional fused predictor blocks ----
// TWO nodes per wave (32 lanes each); 8 lanes/edge (uint4 = 16B), 4 edge groups,
// 16-slot blocks with FOUR row loads in flight per node -> 8 gathers/wave.
// Clamped slots overcount row[col[dgm1]] (only possible in the last block),
// removed by conditional subtracts after the loop.
// Per-edge base redirect: srcs < uth read from the shared buffer xu (user rows
// are bit-identical across s/t chains after each mix), so merged two-list
// dispatches co-access one 12.8MB user region instead of two copies.
__global__ __launch_bounds__(256) void aggp_kernel(
        const u32* __restrict__ x0, const u32* __restrict__ xu0,
        const int* __restrict__ rsA, const u32* __restrict__ colA,
        u32* __restrict__ outA, int nblkA, int nA,
        const u32* __restrict__ x1, const u32* __restrict__ xu1,
        const int* __restrict__ rsB, const u32* __restrict__ colB,
        u32* __restrict__ outB, int nblkB, int nB, int uth,
        const u16* __restrict__ px, const int* __restrict__ l0, const int* __restrict__ l1,
        const float* __restrict__ pw, int ofA, int ofB, float* __restrict__ acc, int nl,
        int npred) {
    int bid = blockIdx.x;
    int lane = threadIdx.x & 63;
    if (bid < npred) {
        int li = bid * 4 + (threadIdx.x >> 6);
        if (li >= nl) return;
        li = __builtin_amdgcn_readfirstlane(li);
        int u = l0[li], v = l1[li];
        float s = pw[ofA + lane] * bf2f(px[(size_t)u * 64 + lane])
                + pw[ofB + lane] * bf2f(px[(size_t)v * 64 + lane]);
#pragma unroll
        for (int off = 32; off > 0; off >>= 1) s += __shfl_xor(s, off, 64);
        if (lane == 0) acc[li] += s;
        return;
    }
    bid -= npred;
    const u32* xin; const u32* xsh; const int* rs; const u32* col; u32* out; int nlim;
    if (bid < nblkA) { xin = x0; xsh = xu0; rs = rsA; col = colA; out = outA; nlim = nA; }
    else { bid -= nblkA; xin = x1; xsh = xu1; rs = rsB; col = colB; out = outB; nlim = nB; }
    int node = bid * 8 + (threadIdx.x >> 5);   // one node per 32-lane half-wave
    if (node >= nlim) return;
    int fl = lane & 7;           // feature octet: features 8fl .. 8fl+7
    int g  = (lane >> 3) & 3;    // edge group 0..3 within the half-wave
    int beg = rs[node];
    int dgv = rs[node + 1] - beg;
    int dgm1 = dgv - 1;
    float a0 = 0.f, a1 = 0.f, a2 = 0.f, a3 = 0.f, a4 = 0.f, a5 = 0.f, a6 = 0.f, a7 = 0.f;
    uint4 p0 = make_uint4(0, 0, 0, 0), p1 = make_uint4(0, 0, 0, 0);
    uint4 p2 = make_uint4(0, 0, 0, 0), p3 = make_uint4(0, 0, 0, 0);
    const uint4* xb  = (const uint4*)xin;
    const uint4* xbu = (const uint4*)xsh;
    if (dgv > 0) {
        int s0 = col[beg + imin(g, dgm1)];
        int s1 = col[beg + imin(g + 4, dgm1)];
        int s2 = col[beg + imin(g + 8, dgm1)];
        int s3 = col[beg + imin(g + 12, dgm1)];
        for (int jb = 0; jb < dgv; jb += 16) {
            p0 = (s0 < uth ? xbu : xb)[(size_t)s0 * 8 + fl];
            p1 = (s1 < uth ? xbu : xb)[(size_t)s1 * 8 + fl];
            p2 = (s2 < uth ? xbu : xb)[(size_t)s2 * 8 + fl];
            p3 = (s3 < uth ? xbu : xb)[(size_t)s3 * 8 + fl];
            int nj = jb + 16 + g;
            s0 = col[beg + imin(nj, dgm1)];       // prefetch next block's cols
            s1 = col[beg + imin(nj + 4, dgm1)];
            s2 = col[beg + imin(nj + 8, dgm1)];
            s3 = col[beg + imin(nj + 12, dgm1)];
            a0 += (flo(p0.x) + flo(p1.x)) + (flo(p2.x) + flo(p3.x));
            a1 += (fhi(p0.x) + fhi(p1.x)) + (fhi(p2.x) + fhi(p3.x));
            a2 += (flo(p0.y) + flo(p1.y)) + (flo(p2.y) + flo(p3.y));
            a3 += (fhi(p0.y) + fhi(p1.y)) + (fhi(p2.y) + fhi(p3.y));
            a4 += (flo(p0.z) + flo(p1.z)) + (flo(p2.z) + flo(p3.z));
            a5 += (fhi(p0.z) + fhi(p1.z)) + (fhi(p2.z) + fhi(p3.z));
            a6 += (flo(p0.w) + flo(p1.w)) + (flo(p2.w) + flo(p3.w));
            a7 += (fhi(p0.w) + fhi(p1.w)) + (fhi(p2.w) + fhi(p3.w));
        }
        int jbl = (dgm1 >> 4) << 4;               // last iteration's block base
        if (jbl + g > dgm1) {
            a0 -= flo(p0.x); a1 -= fhi(p0.x); a2 -= flo(p0.y); a3 -= fhi(p0.y);
            a4 -= flo(p0.z); a5 -= fhi(p0.z); a6 -= flo(p0.w); a7 -= fhi(p0.w);
        }
        if (jbl + 4 + g > dgm1) {
            a0 -= flo(p1.x); a1 -= fhi(p1.x); a2 -= flo(p1.y); a3 -= fhi(p1.y);
            a4 -= flo(p1.z); a5 -= fhi(p1.z); a6 -= flo(p1.w); a7 -= fhi(p1.w);
        }
        if (jbl + 8 + g > dgm1) {
            a0 -= flo(p2.x); a1 -= fhi(p2.x); a2 -= flo(p2.y); a3 -= fhi(p2.y);
            a4 -= flo(p2.z); a5 -= fhi(p2.z); a6 -= flo(p2.w); a7 -= fhi(p2.w);
        }
        if (jbl + 12 + g > dgm1) {
            a0 -= flo(p3.x); a1 -= fhi(p3.x); a2 -= flo(p3.y); a3 -= fhi(p3.y);
            a4 -= flo(p3.z); a5 -= fhi(p3.z); a6 -= flo(p3.w); a7 -= fhi(p3.w);
        }
    }
#pragma unroll
    for (int off = 8; off <= 16; off <<= 1) {     // reduce over 4 edge groups
        a0 += __shfl_xor(a0, off, 64); a1 += __shfl_xor(a1, off, 64);
        a2 += __shfl_xor(a2, off, 64); a3 += __shfl_xor(a3, off, 64);
        a4 += __shfl_xor(a4, off, 64); a5 += __shfl_xor(a5, off, 64);
        a6 += __shfl_xor(a6, off, 64); a7 += __shfl_xor(a7, off, 64);
    }
    if (g == 0) {
        float inv = __builtin_amdgcn_rcpf((float)(dgv > 1 ? dgv : 1));
        uint4 r;
        r.x = pack2(a0 * inv, a1 * inv);
        r.y = pack2(a2 * inv, a3 * inv);
        r.z = pack2(a4 * inv, a5 * inv);
        r.w = pack2(a6 * inv, a7 * inv);
        ((uint4*)out)[(size_t)node * 8 + fl] = r;
    }
}

// ---- user mix via MFMA: one wave = 16 users, K=128 (sbuf||tbuf), 64 outputs ----
// wt=0 skips the tbuf write-back (wide mode: t-chain user rows are dead, gathers
// are redirected to the s-chain buffer).
__global__ __launch_bounds__(256) void mix_mfma(u16* __restrict__ sbuf, u16* __restrict__ tbuf,
        const u16* __restrict__ wb /*[64][128] bf16*/, const float* __restrict__ bias, int nu,
        int wt) {
    int lane = threadIdx.x & 63;
    int wv = threadIdx.x >> 6;
    int m = lane & 15, q = lane >> 4;
    int ubase = blockIdx.x * 64 + wv * 16;
    int ul = ubase + m;
    int usafe = ul < nu ? ul : nu - 1;
    const bf16x8* srow = (const bf16x8*)(sbuf + (size_t)usafe * 64);
    const bf16x8* trow = (const bf16x8*)(tbuf + (size_t)usafe * 64);
    bf16x8 a0 = srow[q];
    bf16x8 a1 = srow[4 + q];
    bf16x8 a2 = trow[q];
    bf16x8 a3 = trow[4 + q];
    f32x4 accv[4];
#pragma unroll
    for (int t = 0; t < 4; ++t) { accv[t].x = accv[t].y = accv[t].z = accv[t].w = 0.f; }
#pragma unroll
    for (int t = 0; t < 4; ++t) {
        const u16* wd = wb + (size_t)(t * 16 + m) * 128;
        accv[t] = __builtin_amdgcn_mfma_f32_16x16x32_bf16(a0, *(const bf16x8*)(wd + q * 8), accv[t], 0, 0, 0);
        accv[t] = __builtin_amdgcn_mfma_f32_16x16x32_bf16(a1, *(const bf16x8*)(wd + 32 + q * 8), accv[t], 0, 0, 0);
        accv[t] = __builtin_amdgcn_mfma_f32_16x16x32_bf16(a2, *(const bf16x8*)(wd + 64 + q * 8), accv[t], 0, 0, 0);
        accv[t] = __builtin_amdgcn_mfma_f32_16x16x32_bf16(a3, *(const bf16x8*)(wd + 96 + q * 8), accv[t], 0, 0, 0);
    }
    int urow = ubase + q * 4;
#pragma unroll
    for (int t = 0; t < 4; ++t) {
        float bv = bias[t * 16 + m];
#pragma unroll
        for (int r = 0; r < 4; ++r) {
            int uu = urow + r;
            if (uu < nu) {
                u16 h = f2bf(accv[t][r] + bv);
                sbuf[(size_t)uu * 64 + t * 16 + m] = h;
                if (wt) tbuf[(size_t)uu * 64 + t * 16 + m] = h;
            }
        }
    }
}

// ---- standalone final predictor ----
__global__ __launch_bounds__(256) void predl_kernel(const u16* __restrict__ xb,
        const int* __restrict__ l0, const int* __restrict__ l1,
        const float* __restrict__ pw, int ofA, int ofB,
        float* __restrict__ acc, int nl,
        const float* __restrict__ pb, float* __restrict__ out) {
    int li = blockIdx.x * 4 + (threadIdx.x >> 6);
    if (li >= nl) return;
    li = __builtin_amdgcn_readfirstlane(li);
    int lane = threadIdx.x & 63;
    int u = l0[li], v = l1[li];
    float s = pw[ofA + lane] * bf2f(xb[(size_t)u * 64 + lane])
            + pw[ofB + lane] * bf2f(xb[(size_t)v * 64 + lane]);
#pragma unroll
    for (int off = 32; off > 0; off >>= 1) s += __shfl_xor(s, off, 64);
    if (lane == 0) {
        float t = acc[li] + s + pb[0];
        t = t > 0.f ? t : 0.01f * t;
        out[li] = 1.f / (1.f + expf(-t));
    }
}

extern "C" void kernel_launch(void* const* d_in, const int* in_sizes, int n_in,
                              void* d_out, int out_size, void* d_ws, size_t ws_size,
                              hipStream_t stream) {
    const int*   se  = (const int*)d_in[0];   // [2,E] src then dst
    const int*   te  = (const int*)d_in[1];
    const int*   lk  = (const int*)d_in[2];   // [2,NLINK]
    const float* emb = (const float*)d_in[3]; // [N,64]
    const float* mw  = (const float*)d_in[4]; // [3,64,128]
    const float* mb  = (const float*)d_in[5]; // [3,64]
    const float* pw  = (const float*)d_in[6]; // [1,512]
    const float* pb  = (const float*)d_in[7]; // [1]
    float* out = (float*)d_out;

    const int E  = in_sizes[0] / 2;
    const int NL = in_sizes[2] / 2;
    const int N  = in_sizes[3] / 64;
    const int U  = 100000;
    const int NB = (N + NODESB - 1) >> BSHIFT;   // 782 coarse buckets

    char* p = (char*)d_ws;
    auto alloc = [&](size_t bytes) -> char* {
        char* r = p;
        p += (bytes + 255) & ~(size_t)255;
        return r;
    };
    u32* A     = (u32*)alloc((size_t)N * 32 * 4);   // bf16 node buf (25.6MB)
    u32* B     = (u32*)alloc((size_t)N * 32 * 4);
    u32* C     = (u32*)alloc((size_t)N * 32 * 4);   // D1: bf16(emb); later chains
    u32* col_s = (u32*)alloc((size_t)E * 4);        // bin -> in-place sorted col
    u32* col_t = (u32*)alloc((size_t)E * 4);
    int* rs_s  = (int*)alloc((size_t)(N + 1) * 4);
    int* rs_t  = (int*)alloc((size_t)(N + 1) * 4);
    float* acc = (float*)alloc((size_t)NL * 4);
    int* gcnt2 = (int*)alloc(2 * NBPAD * 4);
    int* bbase_s = (int*)alloc((NBPAD + 1) * 4);
    int* bbase_t = (int*)alloc((NBPAD + 1) * 4);
    int* cur2  = (int*)alloc(2 * NBPAD * 4);
    u16* mwb   = (u16*)alloc(3 * 64 * 128 * 2);

    // 4th node buffer enables single-dispatch two-list aggregation at L2/L3.
    size_t used  = (size_t)(p - (char*)d_ws);
    size_t nbbuf = (((size_t)N * 32 * 4) + 255) & ~(size_t)255;
    bool wide = (used + nbbuf) <= ws_size;
    u32* Dd = nullptr;
    if (wide) Dd = (u32*)alloc((size_t)N * 32 * 4);

    hipMemsetAsync(gcnt2, 0, 2 * NBPAD * 4, stream);

    const int NHIST = (E + HCHUNK - 1) / HCHUNK;     // 367
    const int NBIN  = (E + BCHUNK - 1) / BCHUNK;     // 367
    const int NWPREP = 96;
    const int NCONV = (N * 64 + 1023) / 1024;        // 12500
    const int GA    = (N + 7) / 8;                   // 25000 agg blocks (8 nodes/block)
    const int GAU   = (U + 7) / 8;                   // 12500 (layer-3 t-agg: users only)
    const int GP    = (NL + 3) / 4;                  // 25000
    const int GM    = (U + 63) / 64;                 // 1563

    // D1: hist both + W prep + emb->bf16 into C
    prep_hist<<<2 * NHIST + NWPREP + NCONV, 256, 0, stream>>>(
        se + E, te + E, E, gcnt2, mw, mwb, emb, C, N * 64, NHIST, NWPREP);
    // D2: parallel bucket scans + pred0
    scan_pred0<<<2 + GP, 256, 0, stream>>>(gcnt2, NB, bbase_s, bbase_t, cur2, rs_s, rs_t,
                                           N, emb, lk, lk + NL, pw, acc, NL);
    // D3: bin both (LDS presort)
    bin3_kernel<<<2 * NBIN, 256, 0, stream>>>(se, se + E, te, te + E, E, cur2, col_s, col_t, NBIN);
    // D4: sort both
    sort2_kernel<<<2 * NB, 256, 0, stream>>>(col_s, col_t, bbase_s, bbase_t, rs_s, rs_t, N, NB);

    if (wide) {
        // L1: merged, both lists from bf16(emb)=C -> A (s1), B (t1)
        aggp_kernel<<<2 * GA, 256, 0, stream>>>(
            C, C, rs_s, col_s, A, GA, N,  C, C, rs_t, col_t, B, GA, N, 0,
            (const u16*)nullptr, nullptr, nullptr, nullptr, 0, 0, nullptr, 0, 0);
        // mix1: write A users only (B user gathers redirect to A below)
        mix_mfma<<<GM, 256, 0, stream>>>((u16*)A, (u16*)B, mwb + 0 * 8192, mb + 0 * 64, U, 0);
        // L2: merged + pred1(A). s: A -> C ; t: B items + A users (redirect) -> Dd
        aggp_kernel<<<GP + 2 * GA, 256, 0, stream>>>(
            A, A, rs_s, col_s, C, GA, N,  B, A, rs_t, col_t, Dd, GA, N, U,
            (const u16*)A, lk, lk + NL, pw, 64, 320, acc, NL, GP);
        // mix2: write C users only
        mix_mfma<<<GM, 256, 0, stream>>>((u16*)C, (u16*)Dd, mwb + 1 * 8192, mb + 1 * 64, U, 0);
        // L3: merged + pred2(C). s: C -> B (all N) ; t: Dd items + C users -> A (users only)
        aggp_kernel<<<GP + GA + GAU, 256, 0, stream>>>(
            C, C, rs_s, col_s, B, GA, N,  Dd, C, rs_t, col_t, A, GAU, U, U,
            (const u16*)C, lk, lk + NL, pw, 128, 384, acc, NL, GP);
        // mix3: write B users only (A dead afterwards)
        mix_mfma<<<GM, 256, 0, stream>>>((u16*)B, (u16*)A, mwb + 2 * 8192, mb + 2 * 64, U, 0);
        // final predictor on B (s-chain L3)
        predl_kernel<<<GP, 256, 0, stream>>>((const u16*)B, lk, lk + NL, pw, 192, 448, acc, NL, pb, out);
    } else {
        // ---- fallback: original 3-buffer sequential schedule ----
        // D5: layer-1 agg, both lists from bf16(emb)=C -> A (s), B (t)
        aggp_kernel<<<2 * GA, 256, 0, stream>>>(
            C, C, rs_s, col_s, A, GA, N,  C, C, rs_t, col_t, B, GA, N, 0,
            (const u16*)nullptr, nullptr, nullptr, nullptr, 0, 0, nullptr, 0, 0);
        // D6: mix1 (A,B user rows)
        mix_mfma<<<GM, 256, 0, stream>>>((u16*)A, (u16*)B, mwb + 0 * 8192, mb + 0 * 64, U, 1);
        // D7: predl1(A) + agg_s L2: A -> C
        aggp_kernel<<<GP + GA, 256, 0, stream>>>(
            A, A, rs_s, col_s, C, GA, N,
            nullptr, nullptr, nullptr, nullptr, nullptr, 0, N, 0,
            (const u16*)A, lk, lk + NL, pw, 64, 320, acc, NL, GP);
        // D8: agg_t L2: B -> A
        aggp_kernel<<<GA, 256, 0, stream>>>(
            B, B, rs_t, col_t, A, GA, N,
            nullptr, nullptr, nullptr, nullptr, nullptr, 0, N, 0,
            (const u16*)nullptr, nullptr, nullptr, nullptr, 0, 0, nullptr, 0, 0);
        // D9: mix2 (C = s-chain, A = t-chain)
        mix_mfma<<<GM, 256, 0, stream>>>((u16*)C, (u16*)A, mwb + 1 * 8192, mb + 1 * 64, U, 1);
        // D10: predl2(C) + agg_s L3: C -> B
        aggp_kernel<<<GP + GA, 256, 0, stream>>>(
            C, C, rs_s, col_s, B, GA, N,
            nullptr, nullptr, nullptr, nullptr, nullptr, 0, N, 0,
            (const u16*)C, lk, lk + NL, pw, 128, 384, acc, NL, GP);
        // D11: agg_t L3 (USER dst rows only): A -> C
        aggp_kernel<<<GAU, 256, 0, stream>>>(
            A, A, rs_t, col_t, C, GAU, U,
            nullptr, nullptr, nullptr, nullptr, nullptr, 0, U, 0,
            (const u16*)nullptr, nullptr, nullptr, nullptr, 0, 0, nullptr, 0, 0);
        // D12: mix3 (B = s-chain, C = t-chain users)
        mix_mfma<<<GM, 256, 0, stream>>>((u16*)B, (u16*)C, mwb + 2 * 8192, mb + 2 * 64, U, 1);
        // D13: final predictor on B (s-chain L3)
        predl_kernel<<<GP, 256, 0, stream>>>((const u16*)B, lk, lk + NL, pw, 192, 448, acc, NL, pb, out);
    }
}

// Round 3
// 677.984 us; speedup vs baseline: 1.0492x; 1.0422x over previous
//
#include <hip/hip_runtime.h>
#include <hip/hip_bf16.h>
#include <math.h>

// N=200000 nodes, U=100000 users, D=64, L=3, E=3,000,000 per edge list, NLINK=100000.
// Wide mode: node buffers as two contiguous PAIRS (A|B, C|Dd), 102.4MB total.
// t-chain gathers use sort-time-remapped col_t (src<U ? src : src+N): user rows are
// read from the shared s-chain lower half (bit-identical after mix), items from the
// pair's upper half -> single base pointer, NO per-gather select (round-2 lesson:
// the select cost 4 VGPR + ~15us/dispatch in a 77% VALUBusy loop).
// L3 s-agg skips nodes not referenced by any link (flag array, ~37% of nodes).

typedef unsigned short u16;
typedef unsigned int   u32;
typedef __attribute__((ext_vector_type(8))) short bf16x8;
typedef __attribute__((ext_vector_type(4))) float f32x4;

#define BSHIFT 8                 // 256 nodes per coarse bucket
#define NODESB 256               // nodes per bucket
#define NBPAD  1024              // padded bucket-count array (782 used)
#define BCAP   4096              // LDS staging per sort bucket (mean ~3840)
#define OVF    8                 // +2048 entries of per-thread register headroom
#define HCHUNK 8192              // edges per hist block
#define BCHUNK 8192              // edges per bin block (LDS presort)

__device__ __forceinline__ float bf2f(u16 v) {
    u32 x = ((u32)v) << 16;
    return __builtin_bit_cast(float, x);
}
__device__ __forceinline__ u16 f2bf(float f) {
    u32 x = __builtin_bit_cast(u32, f);
    u32 r = x + 0x7fffu + ((x >> 16) & 1u);   // round-to-nearest-even
    return (u16)(r >> 16);
}
__device__ __forceinline__ u32 pack2(float a, float b) {
    return (u32)f2bf(a) | ((u32)f2bf(b) << 16);
}
__device__ __forceinline__ float flo(u32 p) { return __builtin_bit_cast(float, p << 16); }
__device__ __forceinline__ float fhi(u32 p) { return __builtin_bit_cast(float, p & 0xffff0000u); }
__device__ __forceinline__ int imin(int a, int b) { return a < b ? a : b; }

// ---- D1: fused hist(s) + hist(t) + W->bf16 prep + emb->bf16 staging ----
__global__ __launch_bounds__(256) void prep_hist(const int* __restrict__ sdst,
        const int* __restrict__ tdst, int e, int* __restrict__ gcnt2,
        const float* __restrict__ mw, u16* __restrict__ mwb,
        const float* __restrict__ emb, u32* __restrict__ embb, int nelem,
        int nhist, int nwprep) {
    __shared__ int lcnt[NBPAD];
    int bid = blockIdx.x, tid = threadIdx.x;
    if (bid < 2 * nhist) {
        const int* dst = (bid < nhist) ? sdst : tdst;
        int* gcnt = gcnt2 + ((bid < nhist) ? 0 : NBPAD);
        int cb = (bid < nhist) ? bid : bid - nhist;
        for (int i = tid; i < NBPAD; i += 256) lcnt[i] = 0;
        __syncthreads();
        int base = cb * HCHUNK, end = imin(base + HCHUNK, e);
        for (int i = base + tid; i < end; i += 256)
            atomicAdd(&lcnt[(u32)dst[i] >> BSHIFT], 1);
        __syncthreads();
        for (int i = tid; i < NBPAD; i += 256)
            if (lcnt[i]) atomicAdd(&gcnt[i], lcnt[i]);
    } else if (bid < 2 * nhist + nwprep) {
        int idx = (bid - 2 * nhist) * 256 + tid;
        if (idx < 3 * 64 * 128) mwb[idx] = f2bf(mw[idx]);
    } else {
        int idx = (bid - 2 * nhist - nwprep) * 1024 + tid * 4;   // 4 floats / thread
        if (idx < nelem) {
            float4 v = *(const float4*)(emb + idx);
            uint2 r;
            r.x = pack2(v.x, v.y);
            r.y = pack2(v.z, v.w);
            *(uint2*)(embb + (idx >> 1)) = r;
        }
    }
}

// ---- D2: parallel bucket scans (2 blocks) + pred0 + link-endpoint flags ----
__global__ __launch_bounds__(256) void scan_pred0(const int* __restrict__ gcnt2, int nb,
        int* __restrict__ bbase_s, int* __restrict__ bbase_t, int* __restrict__ cur2,
        int* __restrict__ rs_s, int* __restrict__ rs_t, int n,
        const float* __restrict__ emb, const int* __restrict__ l0, const int* __restrict__ l1,
        const float* __restrict__ pw, float* __restrict__ acc, int nl,
        unsigned char* __restrict__ flag) {
    int bid = blockIdx.x;
    int tid = threadIdx.x;
    if (bid < 2) {
        __shared__ int part[256];
        const int* g = gcnt2 + bid * NBPAD;
        int* bb = bid ? bbase_t : bbase_s;
        int* cu = cur2 + bid * NBPAD;
        int* rs = bid ? rs_t : rs_s;
        int i0 = tid * 4;
        int c[4]; int s = 0;
#pragma unroll
        for (int j = 0; j < 4; ++j) { c[j] = g[i0 + j]; s += c[j]; }  // zero beyond nb
        part[tid] = s;
        __syncthreads();
        for (int off = 1; off < 256; off <<= 1) {
            int t = (tid >= off) ? part[tid - off] : 0;
            __syncthreads();
            part[tid] += t;
            __syncthreads();
        }
        int excl = part[tid] - s;
#pragma unroll
        for (int j = 0; j < 4; ++j) {
            int idx = i0 + j;
            if (idx <= nb) bb[idx] = excl;
            if (idx < nb)  cu[idx] = excl;
            excl += c[j];
        }
        if (tid == 255) rs[n] = part[255];
        return;
    }
    int li = (bid - 2) * 4 + (tid >> 6);
    if (li >= nl) return;
    li = __builtin_amdgcn_readfirstlane(li);
    int lane = tid & 63;
    int u = l0[li], v = l1[li];
    if (lane == 0) { flag[u] = 1; flag[v] = 1; }   // L3 s-agg liveness
    float s = pw[lane] * emb[(size_t)u * 64 + lane] + pw[256 + lane] * emb[(size_t)v * 64 + lane];
#pragma unroll
    for (int off = 32; off > 0; off >>= 1) s += __shfl_xor(s, off, 64);
    if (lane == 0) acc[li] = s;
}

// ---- D3: binning via block-local LDS presort + coalesced segment flush ----
__global__ __launch_bounds__(256) void bin3_kernel(const int* __restrict__ ssrc,
        const int* __restrict__ sdst, const int* __restrict__ tsrc, const int* __restrict__ tdst,
        int e, int* __restrict__ cur2, u32* __restrict__ bin_s, u32* __restrict__ bin_t,
        int nbin) {
    __shared__ u32 stage[BCHUNK];       // 32KB bucket-sorted staging
    __shared__ int lcnt[NBPAD];         // hist -> scatter cursor
    __shared__ int lofs[NBPAD];         // bucket start within stage
    __shared__ int lbase[NBPAD];        // reserved global base
    __shared__ int part[256];
    int bid = blockIdx.x, tid = threadIdx.x;
    const int* src; const int* dst; int* cursor; u32* bin; int cb;
    if (bid < nbin) { src = ssrc; dst = sdst; cursor = cur2; bin = bin_s; cb = bid; }
    else { src = tsrc; dst = tdst; cursor = cur2 + NBPAD; bin = bin_t; cb = bid - nbin; }
    for (int i = tid; i < NBPAD; i += 256) lcnt[i] = 0;
    __syncthreads();
    int base = cb * BCHUNK, end = imin(base + BCHUNK, e);
    // A: histogram chunk by bucket
    for (int i = base + tid; i < end; i += 256)
        atomicAdd(&lcnt[(u32)dst[i] >> BSHIFT], 1);
    __syncthreads();
    // B: block scan -> lofs; bulk global reservation -> lbase; cursor := lofs
    {
        int i0 = tid * 4;
        int c[4]; int s = 0;
#pragma unroll
        for (int j = 0; j < 4; ++j) { c[j] = lcnt[i0 + j]; s += c[j]; }
        part[tid] = s;
        __syncthreads();
        for (int off = 1; off < 256; off <<= 1) {
            int t = (tid >= off) ? part[tid - off] : 0;
            __syncthreads();
            part[tid] += t;
            __syncthreads();
        }
        int excl = part[tid] - s;
#pragma unroll
        for (int j = 0; j < 4; ++j) {
            int idx = i0 + j;
            lofs[idx]  = excl;
            lbase[idx] = c[j] ? atomicAdd(&cursor[idx], c[j]) : 0;
            lcnt[idx]  = excl;          // scatter cursor starts at bucket start
            excl += c[j];
        }
    }
    __syncthreads();
    // C: scatter entries into LDS staging, bucket-sorted
    for (int i = base + tid; i < end; i += 256) {
        int d = dst[i];
        int b = (u32)d >> BSHIFT;
        int p = atomicAdd(&lcnt[b], 1);
        stage[p] = (u32)src[i] | ((u32)(d & (NODESB - 1)) << 18);   // src < 2^18
    }
    __syncthreads();
    // D: flush segments, 4 lanes per bucket -> contiguous burst writes
    for (int bb = tid >> 2; bb < NBPAD; bb += 64) {
        int lo = lofs[bb];
        int cnt = lcnt[bb] - lo;
        int gb = lbase[bb];
        for (int j = tid & 3; j < cnt; j += 4)
            bin[gb + j] = stage[lo + j];
    }
}

// ---- D4: fused per-bucket counting sort (both lists), in place ----
__global__ __launch_bounds__(256) void sort2_kernel(u32* __restrict__ bin_s, u32* __restrict__ bin_t,
        const int* __restrict__ bbase_s, const int* __restrict__ bbase_t,
        int* __restrict__ rs_s, int* __restrict__ rs_t, int n, int nb) {
    __shared__ u32 ent[BCAP];
    __shared__ int cnt[NODESB];
    __shared__ int part[256];
    int bid = blockIdx.x, tid = threadIdx.x;
    u32* bin; const int* bbase; int* rowstart; int b;
    if (bid < nb) { bin = bin_s; bbase = bbase_s; rowstart = rs_s; b = bid; }
    else { bin = bin_t; bbase = bbase_t; rowstart = rs_t; b = bid - nb; }
    int beg = bbase[b], end = bbase[b + 1];
    int sz = end - beg;
    cnt[tid] = 0;
    __syncthreads();
    u32 ovf[OVF];
    for (int i = tid; i < sz; i += 256) {
        u32 v = bin[beg + i];
        if (i < BCAP) ent[i] = v;
        else { int k = (i - BCAP) >> 8; if (k < OVF) ovf[k] = v; }
        atomicAdd(&cnt[v >> 18], 1);
    }
    __syncthreads();
    int c = cnt[tid];
    part[tid] = c;
    __syncthreads();
    for (int off = 1; off < 256; off <<= 1) {
        int t = (tid >= off) ? part[tid - off] : 0;
        __syncthreads();
        part[tid] += t;
        __syncthreads();
    }
    int excl = part[tid] - c;
    int node = (b << BSHIFT) + tid;
    if (node < n) rowstart[node] = beg + excl;
    cnt[tid] = excl;             // running cursor for scatter phase
    __syncthreads();
    for (int i = tid; i < sz; i += 256) {
        u32 v;
        if (i < BCAP) v = ent[i];
        else { int k = (i - BCAP) >> 8; v = (k < OVF) ? ovf[k] : bin[beg + i]; }
        int pos = atomicAdd(&cnt[v >> 18], 1);
        bin[beg + pos] = v & 0x3FFFFu;
    }
}

// ---- mean aggregation (bf16 in/out) + optional fused predictor blocks ----
// TWO nodes per wave (32 lanes each); 8 lanes/edge (uint4 = 16B), 4 edge groups,
// 16-slot blocks with FOUR row loads in flight per node -> 8 gathers/wave.
// Clamped slots overcount row[col[dgm1]] (removed by conditional subtracts).
// Redirects are pre-baked into col entries (t-list: src<U?src:src+N over a pair
// buffer) -> inner loop has NO selects. skipA: optional per-node liveness for
// list A (L3 s-agg: only link-referenced nodes are ever read downstream).
__global__ __launch_bounds__(256) void aggp_kernel(
        const u32* __restrict__ x0, const int* __restrict__ rsA, const u32* __restrict__ colA,
        u32* __restrict__ outA, int nblkA, int nA, const unsigned char* __restrict__ skipA,
        const u32* __restrict__ x1, const int* __restrict__ rsB, const u32* __restrict__ colB,
        u32* __restrict__ outB, int nblkB, int nB,
        const u16* __restrict__ px, const int* __restrict__ l0, const int* __restrict__ l1,
        const float* __restrict__ pw, int ofA, int ofB, float* __restrict__ acc, int nl,
        int npred) {
    int bid = blockIdx.x;
    int lane = threadIdx.x & 63;
    if (bid < npred) {
        int li = bid * 4 + (threadIdx.x >> 6);
        if (li >= nl) return;
        li = __builtin_amdgcn_readfirstlane(li);
        int u = l0[li], v = l1[li];
        float s = pw[ofA + lane] * bf2f(px[(size_t)u * 64 + lane])
                + pw[ofB + lane] * bf2f(px[(size_t)v * 64 + lane]);
#pragma unroll
        for (int off = 32; off > 0; off >>= 1) s += __shfl_xor(s, off, 64);
        if (lane == 0) acc[li] += s;
        return;
    }
    bid -= npred;
    const u32* xin; const int* rs; const u32* col; u32* out; int nlim;
    const unsigned char* skip = nullptr;
    if (bid < nblkA) { xin = x0; rs = rsA; col = colA; out = outA; nlim = nA; skip = skipA; }
    else { bid -= nblkA; xin = x1; rs = rsB; col = colB; out = outB; nlim = nB; }
    int node = bid * 8 + (threadIdx.x >> 5);   // one node per 32-lane half-wave
    if (node >= nlim) return;
    if (skip && !skip[node]) return;           // output never read downstream
    int fl = lane & 7;           // feature octet: features 8fl .. 8fl+7
    int g  = (lane >> 3) & 3;    // edge group 0..3 within the half-wave
    int beg = rs[node];
    int dgv = rs[node + 1] - beg;
    int dgm1 = dgv - 1;
    float a0 = 0.f, a1 = 0.f, a2 = 0.f, a3 = 0.f, a4 = 0.f, a5 = 0.f, a6 = 0.f, a7 = 0.f;
    uint4 p0 = make_uint4(0, 0, 0, 0), p1 = make_uint4(0, 0, 0, 0);
    uint4 p2 = make_uint4(0, 0, 0, 0), p3 = make_uint4(0, 0, 0, 0);
    const uint4* xb = (const uint4*)xin;
    if (dgv > 0) {
        int s0 = col[beg + imin(g, dgm1)];
        int s1 = col[beg + imin(g + 4, dgm1)];
        int s2 = col[beg + imin(g + 8, dgm1)];
        int s3 = col[beg + imin(g + 12, dgm1)];
        for (int jb = 0; jb < dgv; jb += 16) {
            p0 = xb[(size_t)s0 * 8 + fl];
            p1 = xb[(size_t)s1 * 8 + fl];
            p2 = xb[(size_t)s2 * 8 + fl];
            p3 = xb[(size_t)s3 * 8 + fl];
            int nj = jb + 16 + g;
            s0 = col[beg + imin(nj, dgm1)];       // prefetch next block's cols
            s1 = col[beg + imin(nj + 4, dgm1)];
            s2 = col[beg + imin(nj + 8, dgm1)];
            s3 = col[beg + imin(nj + 12, dgm1)];
            a0 += (flo(p0.x) + flo(p1.x)) + (flo(p2.x) + flo(p3.x));
            a1 += (fhi(p0.x) + fhi(p1.x)) + (fhi(p2.x) + fhi(p3.x));
            a2 += (flo(p0.y) + flo(p1.y)) + (flo(p2.y) + flo(p3.y));
            a3 += (fhi(p0.y) + fhi(p1.y)) + (fhi(p2.y) + fhi(p3.y));
            a4 += (flo(p0.z) + flo(p1.z)) + (flo(p2.z) + flo(p3.z));
            a5 += (fhi(p0.z) + fhi(p1.z)) + (fhi(p2.z) + fhi(p3.z));
            a6 += (flo(p0.w) + flo(p1.w)) + (flo(p2.w) + flo(p3.w));
            a7 += (fhi(p0.w) + fhi(p1.w)) + (fhi(p2.w) + fhi(p3.w));
        }
        int jbl = (dgm1 >> 4) << 4;               // last iteration's block base
        if (jbl + g > dgm1) {
            a0 -= flo(p0.x); a1 -= fhi(p0.x); a2 -= flo(p0.y); a3 -= fhi(p0.y);
            a4 -= flo(p0.z); a5 -= fhi(p0.z); a6 -= flo(p0.w); a7 -= fhi(p0.w);
        }
        if (jbl + 4 + g > dgm1) {
            a0 -= flo(p1.x); a1 -= fhi(p1.x); a2 -= flo(p1.y); a3 -= fhi(p1.y);
            a4 -= flo(p1.z); a5 -= fhi(p1.z); a6 -= flo(p1.w); a7 -= fhi(p1.w);
        }
        if (jbl + 8 + g > dgm1) {
            a0 -= flo(p2.x); a1 -= fhi(p2.x); a2 -= flo(p2.y); a3 -= fhi(p2.y);
            a4 -= flo(p2.z); a5 -= fhi(p2.z); a6 -= flo(p2.w); a7 -= fhi(p2.w);
        }
        if (jbl + 12 + g > dgm1) {
            a0 -= flo(p3.x); a1 -= fhi(p3.x); a2 -= flo(p3.y); a3 -= fhi(p3.y);
            a4 -= flo(p3.z); a5 -= fhi(p3.z); a6 -= flo(p3.w); a7 -= fhi(p3.w);
        }
    }
#pragma unroll
    for (int off = 8; off <= 16; off <<= 1) {     // reduce over 4 edge groups
        a0 += __shfl_xor(a0, off, 64); a1 += __shfl_xor(a1, off, 64);
        a2 += __shfl_xor(a2, off, 64); a3 += __shfl_xor(a3, off, 64);
        a4 += __shfl_xor(a4, off, 64); a5 += __shfl_xor(a5, off, 64);
        a6 += __shfl_xor(a6, off, 64); a7 += __shfl_xor(a7, off, 64);
    }
    if (g == 0) {
        float inv = __builtin_amdgcn_rcpf((float)(dgv > 1 ? dgv : 1));
        uint4 r;
        r.x = pack2(a0 * inv, a1 * inv);
        r.y = pack2(a2 * inv, a3 * inv);
        r.z = pack2(a4 * inv, a5 * inv);
        r.w = pack2(a6 * inv, a7 * inv);
        ((uint4*)out)[(size_t)node * 8 + fl] = r;
    }
}

// ---- user mix via MFMA + optional fused col_t remap blocks ----
// One wave = 16 users, K=128 (sbuf||tbuf), 64 outputs. wt=0 skips tbuf write-back
// (wide mode: t-chain user rows dead, gathers redirected via remapped cols).
// First nrb blocks: col_t[i] = e<uu ? e : e+nn (runs after L1 consumed raw col_t).
__global__ __launch_bounds__(256) void mix_mfma(u16* __restrict__ sbuf, u16* __restrict__ tbuf,
        const u16* __restrict__ wb /*[64][128] bf16*/, const float* __restrict__ bias, int nu,
        int wt, u32* __restrict__ colt, int ecnt, int nrb, u32 uu, u32 nn) {
    int bid = blockIdx.x;
    if (bid < nrb) {
        int idx = (bid * 256 + (int)threadIdx.x) * 4;
        if (idx + 3 < ecnt) {
            uint4 v = *(uint4*)(colt + idx);
            v.x = v.x >= uu ? v.x + nn : v.x;
            v.y = v.y >= uu ? v.y + nn : v.y;
            v.z = v.z >= uu ? v.z + nn : v.z;
            v.w = v.w >= uu ? v.w + nn : v.w;
            *(uint4*)(colt + idx) = v;
        } else {
            for (int k = idx; k < ecnt; ++k) { u32 e = colt[k]; colt[k] = e >= uu ? e + nn : e; }
        }
        return;
    }
    bid -= nrb;
    int lane = threadIdx.x & 63;
    int wv = threadIdx.x >> 6;
    int m = lane & 15, q = lane >> 4;
    int ubase = bid * 64 + wv * 16;
    int ul = ubase + m;
    int usafe = ul < nu ? ul : nu - 1;
    const bf16x8* srow = (const bf16x8*)(sbuf + (size_t)usafe * 64);
    const bf16x8* trow = (const bf16x8*)(tbuf + (size_t)usafe * 64);
    bf16x8 a0 = srow[q];
    bf16x8 a1 = srow[4 + q];
    bf16x8 a2 = trow[q];
    bf16x8 a3 = trow[4 + q];
    f32x4 accv[4];
#pragma unroll
    for (int t = 0; t < 4; ++t) { accv[t].x = accv[t].y = accv[t].z = accv[t].w = 0.f; }
#pragma unroll
    for (int t = 0; t < 4; ++t) {
        const u16* wd = wb + (size_t)(t * 16 + m) * 128;
        accv[t] = __builtin_amdgcn_mfma_f32_16x16x32_bf16(a0, *(const bf16x8*)(wd + q * 8), accv[t], 0, 0, 0);
        accv[t] = __builtin_amdgcn_mfma_f32_16x16x32_bf16(a1, *(const bf16x8*)(wd + 32 + q * 8), accv[t], 0, 0, 0);
        accv[t] = __builtin_amdgcn_mfma_f32_16x16x32_bf16(a2, *(const bf16x8*)(wd + 64 + q * 8), accv[t], 0, 0, 0);
        accv[t] = __builtin_amdgcn_mfma_f32_16x16x32_bf16(a3, *(const bf16x8*)(wd + 96 + q * 8), accv[t], 0, 0, 0);
    }
    int urow = ubase + q * 4;
#pragma unroll
    for (int t = 0; t < 4; ++t) {
        float bv = bias[t * 16 + m];
#pragma unroll
        for (int r = 0; r < 4; ++r) {
            int uu2 = urow + r;
            if (uu2 < nu) {
                u16 h = f2bf(accv[t][r] + bv);
                sbuf[(size_t)uu2 * 64 + t * 16 + m] = h;
                if (wt) tbuf[(size_t)uu2 * 64 + t * 16 + m] = h;
            }
        }
    }
}

// ---- standalone final predictor ----
__global__ __launch_bounds__(256) void predl_kernel(const u16* __restrict__ xb,
        const int* __restrict__ l0, const int* __restrict__ l1,
        const float* __restrict__ pw, int ofA, int ofB,
        float* __restrict__ acc, int nl,
        const float* __restrict__ pb, float* __restrict__ out) {
    int li = blockIdx.x * 4 + (threadIdx.x >> 6);
    if (li >= nl) return;
    li = __builtin_amdgcn_readfirstlane(li);
    int lane = threadIdx.x & 63;
    int u = l0[li], v = l1[li];
    float s = pw[ofA + lane] * bf2f(xb[(size_t)u * 64 + lane])
            + pw[ofB + lane] * bf2f(xb[(size_t)v * 64 + lane]);
#pragma unroll
    for (int off = 32; off > 0; off >>= 1) s += __shfl_xor(s, off, 64);
    if (lane == 0) {
        float t = acc[li] + s + pb[0];
        t = t > 0.f ? t : 0.01f * t;
        out[li] = 1.f / (1.f + expf(-t));
    }
}

extern "C" void kernel_launch(void* const* d_in, const int* in_sizes, int n_in,
                              void* d_out, int out_size, void* d_ws, size_t ws_size,
                              hipStream_t stream) {
    const int*   se  = (const int*)d_in[0];   // [2,E] src then dst
    const int*   te  = (const int*)d_in[1];
    const int*   lk  = (const int*)d_in[2];   // [2,NLINK]
    const float* emb = (const float*)d_in[3]; // [N,64]
    const float* mw  = (const float*)d_in[4]; // [3,64,128]
    const float* mb  = (const float*)d_in[5]; // [3,64]
    const float* pw  = (const float*)d_in[6]; // [1,512]
    const float* pb  = (const float*)d_in[7]; // [1]
    float* out = (float*)d_out;

    const int E  = in_sizes[0] / 2;
    const int NL = in_sizes[2] / 2;
    const int N  = in_sizes[3] / 64;
    const int U  = 100000;
    const int NB = (N + NODESB - 1) >> BSHIFT;   // 782 coarse buckets

    char* p = (char*)d_ws;
    auto alloc = [&](size_t bytes) -> char* {
        char* r = p;
        p += (bytes + 255) & ~(size_t)255;
        return r;
    };
    const size_t bufb = (size_t)N * 128;                    // one node buffer, bytes
    const bool contig = (bufb % 256) == 0;                  // pair layout needs no pad
    const size_t pad = [&](size_t b) { return (b + 255) & ~(size_t)255; }(0), _unused = pad;
    auto rnd = [](size_t b) { return (b + 255) & ~(size_t)255; };
    size_t wide_total = 4 * rnd(bufb) + 2 * rnd((size_t)E * 4) + 2 * rnd((size_t)(N + 1) * 4)
                      + rnd((size_t)NL * 4) + rnd(2 * NBPAD * 4) + 2 * rnd((NBPAD + 1) * 4)
                      + rnd(2 * NBPAD * 4) + rnd(3 * 64 * 128 * 2) + rnd((size_t)N);
    bool wide = contig && (wide_total <= ws_size);

    u32 *A, *B, *C, *Dd = nullptr;
    if (wide) {
        A  = (u32*)alloc(bufb);   // pair P1 = [A | B]   (s-chain | t-chain)
        B  = (u32*)alloc(bufb);
        C  = (u32*)alloc(bufb);   // pair P2 = [C | Dd]
        Dd = (u32*)alloc(bufb);
    } else {
        A  = (u32*)alloc(bufb);
        B  = (u32*)alloc(bufb);
        C  = (u32*)alloc(bufb);
    }
    u32* col_s = (u32*)alloc((size_t)E * 4);
    u32* col_t = (u32*)alloc((size_t)E * 4);
    int* rs_s  = (int*)alloc((size_t)(N + 1) * 4);
    int* rs_t  = (int*)alloc((size_t)(N + 1) * 4);
    float* acc = (float*)alloc((size_t)NL * 4);
    int* gcnt2 = (int*)alloc(2 * NBPAD * 4);
    int* bbase_s = (int*)alloc((NBPAD + 1) * 4);
    int* bbase_t = (int*)alloc((NBPAD + 1) * 4);
    int* cur2  = (int*)alloc(2 * NBPAD * 4);
    u16* mwb   = (u16*)alloc(3 * 64 * 128 * 2);
    unsigned char* flags = (unsigned char*)alloc((size_t)N);

    hipMemsetAsync(gcnt2, 0, 2 * NBPAD * 4, stream);
    hipMemsetAsync(flags, 0, (size_t)N, stream);

    const int NHIST = (E + HCHUNK - 1) / HCHUNK;     // 367
    const int NBIN  = (E + BCHUNK - 1) / BCHUNK;     // 367
    const int NWPREP = 96;
    const int NCONV = (N * 64 + 1023) / 1024;        // 12500
    const int GA    = (N + 7) / 8;                   // 25000 agg blocks (8 nodes/block)
    const int GAU   = (U + 7) / 8;                   // 12500 (layer-3 t-agg: users only)
    const int GP    = (NL + 3) / 4;                  // 25000
    const int GM    = (U + 63) / 64;                 // 1563
    const int NRB   = (E + 1023) / 1024;             // 2930 remap blocks (4 entries/thread)

    // D1: hist both + W prep + emb->bf16 into C (P2 lower)
    prep_hist<<<2 * NHIST + NWPREP + NCONV, 256, 0, stream>>>(
        se + E, te + E, E, gcnt2, mw, mwb, emb, C, N * 64, NHIST, NWPREP);
    // D2: parallel bucket scans + pred0 + link flags
    scan_pred0<<<2 + GP, 256, 0, stream>>>(gcnt2, NB, bbase_s, bbase_t, cur2, rs_s, rs_t,
                                           N, emb, lk, lk + NL, pw, acc, NL, flags);
    // D3: bin both (LDS presort)
    bin3_kernel<<<2 * NBIN, 256, 0, stream>>>(se, se + E, te, te + E, E, cur2, col_s, col_t, NBIN);
    // D4: sort both
    sort2_kernel<<<2 * NB, 256, 0, stream>>>(col_s, col_t, bbase_s, bbase_t, rs_s, rs_t, N, NB);

    if (wide) {
        // L1 merged: both lists gather C (full sharing, unmapped cols) -> A (s1), B (t1)
        aggp_kernel<<<2 * GA, 256, 0, stream>>>(
            C, rs_s, col_s, A, GA, N, nullptr,  C, rs_t, col_t, B, GA, N,
            (const u16*)nullptr, nullptr, nullptr, nullptr, 0, 0, nullptr, 0, 0);
        // mix1 (write A users only) + col_t remap (src<U ? src : src+N)
        mix_mfma<<<GM + NRB, 256, 0, stream>>>((u16*)A, (u16*)B, mwb + 0 * 8192, mb + 0 * 64,
                                               U, 0, col_t, E, NRB, (u32)U, (u32)N);
        // L2 merged + pred1(A): s: base A, col_s -> C ; t: base A (remapped col_t spans A|B) -> Dd
        aggp_kernel<<<GP + 2 * GA, 256, 0, stream>>>(
            A, rs_s, col_s, C, GA, N, nullptr,  A, rs_t, col_t, Dd, GA, N,
            (const u16*)A, lk, lk + NL, pw, 64, 320, acc, NL, GP);
        // mix2 (write C users only)
        mix_mfma<<<GM, 256, 0, stream>>>((u16*)C, (u16*)Dd, mwb + 1 * 8192, mb + 1 * 64,
                                         U, 0, nullptr, 0, 0, 0, 0);
        // L3 merged + pred2(C): s: base C, col_s -> A (link-flagged nodes only) ;
        //                       t: base C (remapped col_t spans C|Dd) -> B (users only)
        aggp_kernel<<<GP + GA + GAU, 256, 0, stream>>>(
            C, rs_s, col_s, A, GA, N, flags,  C, rs_t, col_t, B, GAU, U,
            (const u16*)C, lk, lk + NL, pw, 128, 384, acc, NL, GP);
        // mix3 (write A users only; unflagged users compute garbage, never read)
        mix_mfma<<<GM, 256, 0, stream>>>((u16*)A, (u16*)B, mwb + 2 * 8192, mb + 2 * 64,
                                         U, 0, nullptr, 0, 0, 0, 0);
        // final predictor on A (s-chain L3 mixed)
        predl_kernel<<<GP, 256, 0, stream>>>((const u16*)A, lk, lk + NL, pw, 192, 448, acc, NL, pb, out);
    } else {
        // ---- fallback: 3-buffer sequential schedule, unmapped cols ----
        aggp_kernel<<<2 * GA, 256, 0, stream>>>(
            C, rs_s, col_s, A, GA, N, nullptr,  C, rs_t, col_t, B, GA, N,
            (const u16*)nullptr, nullptr, nullptr, nullptr, 0, 0, nullptr, 0, 0);
        mix_mfma<<<GM, 256, 0, stream>>>((u16*)A, (u16*)B, mwb + 0 * 8192, mb + 0 * 64,
                                         U, 1, nullptr, 0, 0, 0, 0);
        aggp_kernel<<<GP + GA, 256, 0, stream>>>(
            A, rs_s, col_s, C, GA, N, nullptr,
            nullptr, nullptr, nullptr, nullptr, 0, 0,
            (const u16*)A, lk, lk + NL, pw, 64, 320, acc, NL, GP);
        aggp_kernel<<<GA, 256, 0, stream>>>(
            B, rs_t, col_t, A, GA, N, nullptr,
            nullptr, nullptr, nullptr, nullptr, 0, 0,
            (const u16*)nullptr, nullptr, nullptr, nullptr, 0, 0, nullptr, 0, 0);
        mix_mfma<<<GM, 256, 0, stream>>>((u16*)C, (u16*)A, mwb + 1 * 8192, mb + 1 * 64,
                                         U, 1, nullptr, 0, 0, 0, 0);
        aggp_kernel<<<GP + GA, 256, 0, stream>>>(
            C, rs_s, col_s, B, GA, N, nullptr,
            nullptr, nullptr, nullptr, nullptr, 0, 0,
            (const u16*)C, lk, lk + NL, pw, 128, 384, acc, NL, GP);
        aggp_kernel<<<GAU, 256, 0, stream>>>(
            A, rs_t, col_t, C, GAU, U, nullptr,
            nullptr, nullptr, nullptr, nullptr, 0, 0,
            (const u16*)nullptr, nullptr, nullptr, nullptr, 0, 0, nullptr, 0, 0);
        mix_mfma<<<GM, 256, 0, stream>>>((u16*)B, (u16*)C, mwb + 2 * 8192, mb + 2 * 64,
                                         U, 1, nullptr, 0, 0, 0, 0);
        predl_kernel<<<GP, 256, 0, stream>>>((const u16*)B, lk, lk + NL, pw, 192, 448, acc, NL, pb, out);
    }
}

// Round 5
// 672.633 us; speedup vs baseline: 1.0576x; 1.0080x over previous
//
#include <hip/hip_runtime.h>
#include <hip/hip_bf16.h>
#include <math.h>

// N=200000 nodes, U=100000 users, D=64, L=3, E=3,000,000 per edge list, NLINK=100000.
// Node buffers are FP16 (not bf16): inner aggregation accumulates via
// v_dot2_f32_f16 (1 VALU op per feature vs unpack+add), strictly better accuracy.
// Agg mapping: 16 lanes/node (8 feature-lanes x 2 edge groups), 4 nodes/wave,
// 4 row-loads in flight per node -> 16 outstanding gathers/wave (2x round-3 MLP).
// Wide mode: node buffers as two contiguous PAIRS (A|B, C|Dd); t-chain gathers use
// remapped col_t (src<U ? src : src+N) so user rows are shared with the s-chain
// (bit-identical after mix) with a single base pointer, no per-gather select.
// L3 s-agg skips nodes not referenced by any link (flag array).

typedef unsigned short u16;
typedef unsigned int   u32;
typedef __attribute__((ext_vector_type(2))) _Float16 h16x2;
typedef __attribute__((ext_vector_type(8))) _Float16 f16x8;
typedef __attribute__((ext_vector_type(4))) float f32x4;

#define BSHIFT 8                 // 256 nodes per coarse bucket
#define NODESB 256               // nodes per bucket
#define NBPAD  1024              // padded bucket-count array (782 used)
#define BCAP   4096              // LDS staging per sort bucket (mean ~3840)
#define OVF    8                 // +2048 entries of per-thread register headroom
#define HCHUNK 8192              // edges per hist block
#define BCHUNK 8192              // edges per bin block (LDS presort)

__device__ __forceinline__ u16 f2h(float f) {
    _Float16 h = (_Float16)f;
    return __builtin_bit_cast(u16, h);
}
__device__ __forceinline__ float h2f(u16 v) {
    _Float16 h = __builtin_bit_cast(_Float16, v);
    return (float)h;
}
__device__ __forceinline__ u32 packh2(float a, float b) {
    auto r = __builtin_amdgcn_cvt_pkrtz(a, b);   // v_cvt_pkrtz_f16_f32 (__fp16 x2)
    return __builtin_bit_cast(u32, r);
}
__device__ __forceinline__ float hlo(u32 p) {
    h16x2 h = __builtin_bit_cast(h16x2, p);
    return (float)h.x;
}
__device__ __forceinline__ float hhi(u32 p) {
    h16x2 h = __builtin_bit_cast(h16x2, p);
    return (float)h.y;
}
__device__ __forceinline__ int imin(int a, int b) { return a < b ? a : b; }

#if defined(__has_builtin)
#if __has_builtin(__builtin_amdgcn_fdot2)
#define HAVE_FDOT2 1
#endif
#endif

// ---- D1: fused hist(s) + hist(t) + W->f16 prep + emb->f16 staging ----
__global__ __launch_bounds__(256) void prep_hist(const int* __restrict__ sdst,
        const int* __restrict__ tdst, int e, int* __restrict__ gcnt2,
        const float* __restrict__ mw, u16* __restrict__ mwb,
        const float* __restrict__ emb, u32* __restrict__ embb, int nelem,
        int nhist, int nwprep) {
    __shared__ int lcnt[NBPAD];
    int bid = blockIdx.x, tid = threadIdx.x;
    if (bid < 2 * nhist) {
        const int* dst = (bid < nhist) ? sdst : tdst;
        int* gcnt = gcnt2 + ((bid < nhist) ? 0 : NBPAD);
        int cb = (bid < nhist) ? bid : bid - nhist;
        for (int i = tid; i < NBPAD; i += 256) lcnt[i] = 0;
        __syncthreads();
        int base = cb * HCHUNK, end = imin(base + HCHUNK, e);
        for (int i = base + tid; i < end; i += 256)
            atomicAdd(&lcnt[(u32)dst[i] >> BSHIFT], 1);
        __syncthreads();
        for (int i = tid; i < NBPAD; i += 256)
            if (lcnt[i]) atomicAdd(&gcnt[i], lcnt[i]);
    } else if (bid < 2 * nhist + nwprep) {
        int idx = (bid - 2 * nhist) * 256 + tid;
        if (idx < 3 * 64 * 128) mwb[idx] = f2h(mw[idx]);
    } else {
        int idx = (bid - 2 * nhist - nwprep) * 1024 + tid * 4;   // 4 floats / thread
        if (idx < nelem) {
            float4 v = *(const float4*)(emb + idx);
            uint2 r;
            r.x = packh2(v.x, v.y);
            r.y = packh2(v.z, v.w);
            *(uint2*)(embb + (idx >> 1)) = r;
        }
    }
}

// ---- D2: parallel bucket scans (2 blocks) + pred0 + link-endpoint flags ----
__global__ __launch_bounds__(256) void scan_pred0(const int* __restrict__ gcnt2, int nb,
        int* __restrict__ bbase_s, int* __restrict__ bbase_t, int* __restrict__ cur2,
        int* __restrict__ rs_s, int* __restrict__ rs_t, int n,
        const float* __restrict__ emb, const int* __restrict__ l0, const int* __restrict__ l1,
        const float* __restrict__ pw, float* __restrict__ acc, int nl,
        unsigned char* __restrict__ flag) {
    int bid = blockIdx.x;
    int tid = threadIdx.x;
    if (bid < 2) {
        __shared__ int part[256];
        const int* g = gcnt2 + bid * NBPAD;
        int* bb = bid ? bbase_t : bbase_s;
        int* cu = cur2 + bid * NBPAD;
        int* rs = bid ? rs_t : rs_s;
        int i0 = tid * 4;
        int c[4]; int s = 0;
#pragma unroll
        for (int j = 0; j < 4; ++j) { c[j] = g[i0 + j]; s += c[j]; }  // zero beyond nb
        part[tid] = s;
        __syncthreads();
        for (int off = 1; off < 256; off <<= 1) {
            int t = (tid >= off) ? part[tid - off] : 0;
            __syncthreads();
            part[tid] += t;
            __syncthreads();
        }
        int excl = part[tid] - s;
#pragma unroll
        for (int j = 0; j < 4; ++j) {
            int idx = i0 + j;
            if (idx <= nb) bb[idx] = excl;
            if (idx < nb)  cu[idx] = excl;
            excl += c[j];
        }
        if (tid == 255) rs[n] = part[255];
        return;
    }
    int li = (bid - 2) * 4 + (tid >> 6);
    if (li >= nl) return;
    li = __builtin_amdgcn_readfirstlane(li);
    int lane = tid & 63;
    int u = l0[li], v = l1[li];
    if (lane == 0) { flag[u] = 1; flag[v] = 1; }   // L3 s-agg liveness
    float s = pw[lane] * emb[(size_t)u * 64 + lane] + pw[256 + lane] * emb[(size_t)v * 64 + lane];
#pragma unroll
    for (int off = 32; off > 0; off >>= 1) s += __shfl_xor(s, off, 64);
    if (lane == 0) acc[li] = s;
}

// ---- D3: binning via block-local LDS presort + coalesced segment flush ----
__global__ __launch_bounds__(256) void bin3_kernel(const int* __restrict__ ssrc,
        const int* __restrict__ sdst, const int* __restrict__ tsrc, const int* __restrict__ tdst,
        int e, int* __restrict__ cur2, u32* __restrict__ bin_s, u32* __restrict__ bin_t,
        int nbin) {
    __shared__ u32 stage[BCHUNK];       // 32KB bucket-sorted staging
    __shared__ int lcnt[NBPAD];         // hist -> scatter cursor
    __shared__ int lofs[NBPAD];         // bucket start within stage
    __shared__ int lbase[NBPAD];        // reserved global base
    __shared__ int part[256];
    int bid = blockIdx.x, tid = threadIdx.x;
    const int* src; const int* dst; int* cursor; u32* bin; int cb;
    if (bid < nbin) { src = ssrc; dst = sdst; cursor = cur2; bin = bin_s; cb = bid; }
    else { src = tsrc; dst = tdst; cursor = cur2 + NBPAD; bin = bin_t; cb = bid - nbin; }
    for (int i = tid; i < NBPAD; i += 256) lcnt[i] = 0;
    __syncthreads();
    int base = cb * BCHUNK, end = imin(base + BCHUNK, e);
    // A: histogram chunk by bucket
    for (int i = base + tid; i < end; i += 256)
        atomicAdd(&lcnt[(u32)dst[i] >> BSHIFT], 1);
    __syncthreads();
    // B: block scan -> lofs; bulk global reservation -> lbase; cursor := lofs
    {
        int i0 = tid * 4;
        int c[4]; int s = 0;
#pragma unroll
        for (int j = 0; j < 4; ++j) { c[j] = lcnt[i0 + j]; s += c[j]; }
        part[tid] = s;
        __syncthreads();
        for (int off = 1; off < 256; off <<= 1) {
            int t = (tid >= off) ? part[tid - off] : 0;
            __syncthreads();
            part[tid] += t;
            __syncthreads();
        }
        int excl = part[tid] - s;
#pragma unroll
        for (int j = 0; j < 4; ++j) {
            int idx = i0 + j;
            lofs[idx]  = excl;
            lbase[idx] = c[j] ? atomicAdd(&cursor[idx], c[j]) : 0;
            lcnt[idx]  = excl;          // scatter cursor starts at bucket start
            excl += c[j];
        }
    }
    __syncthreads();
    // C: scatter entries into LDS staging, bucket-sorted
    for (int i = base + tid; i < end; i += 256) {
        int d = dst[i];
        int b = (u32)d >> BSHIFT;
        int p = atomicAdd(&lcnt[b], 1);
        stage[p] = (u32)src[i] | ((u32)(d & (NODESB - 1)) << 18);   // src < 2^18
    }
    __syncthreads();
    // D: flush segments, 4 lanes per bucket -> contiguous burst writes
    for (int bb = tid >> 2; bb < NBPAD; bb += 64) {
        int lo = lofs[bb];
        int cnt = lcnt[bb] - lo;
        int gb = lbase[bb];
        for (int j = tid & 3; j < cnt; j += 4)
            bin[gb + j] = stage[lo + j];
    }
}

// ---- D4: fused per-bucket counting sort (both lists), in place ----
__global__ __launch_bounds__(256) void sort2_kernel(u32* __restrict__ bin_s, u32* __restrict__ bin_t,
        const int* __restrict__ bbase_s, const int* __restrict__ bbase_t,
        int* __restrict__ rs_s, int* __restrict__ rs_t, int n, int nb) {
    __shared__ u32 ent[BCAP];
    __shared__ int cnt[NODESB];
    __shared__ int part[256];
    int bid = blockIdx.x, tid = threadIdx.x;
    u32* bin; const int* bbase; int* rowstart; int b;
    if (bid < nb) { bin = bin_s; bbase = bbase_s; rowstart = rs_s; b = bid; }
    else { bin = bin_t; bbase = bbase_t; rowstart = rs_t; b = bid - nb; }
    int beg = bbase[b], end = bbase[b + 1];
    int sz = end - beg;
    cnt[tid] = 0;
    __syncthreads();
    u32 ovf[OVF];
    for (int i = tid; i < sz; i += 256) {
        u32 v = bin[beg + i];
        if (i < BCAP) ent[i] = v;
        else { int k = (i - BCAP) >> 8; if (k < OVF) ovf[k] = v; }
        atomicAdd(&cnt[v >> 18], 1);
    }
    __syncthreads();
    int c = cnt[tid];
    part[tid] = c;
    __syncthreads();
    for (int off = 1; off < 256; off <<= 1) {
        int t = (tid >= off) ? part[tid - off] : 0;
        __syncthreads();
        part[tid] += t;
        __syncthreads();
    }
    int excl = part[tid] - c;
    int node = (b << BSHIFT) + tid;
    if (node < n) rowstart[node] = beg + excl;
    cnt[tid] = excl;             // running cursor for scatter phase
    __syncthreads();
    for (int i = tid; i < sz; i += 256) {
        u32 v;
        if (i < BCAP) v = ent[i];
        else { int k = (i - BCAP) >> 8; v = (k < OVF) ? ovf[k] : bin[beg + i]; }
        int pos = atomicAdd(&cnt[v >> 18], 1);
        bin[beg + pos] = v & 0x3FFFFu;
    }
}

// ---- mean aggregation (f16 in/out, fdot2 accumulate) + fused predictors ----
// 16 lanes per node (8 feature-lanes x 2 edge groups), 4 nodes/wave; 8-slot
// blocks with FOUR row loads in flight per node -> 16 gathers/wave outstanding.
// Accumulate: v_dot2_f32_f16 with (1,0)/(0,1) selectors = 1 op/feature, exact
// f16->f32 convert. Clamped slots overcount row[col[dgm1]] (only in the last
// block), removed by conditional exact subtracts after the loop.
__global__ __launch_bounds__(256) void aggp_kernel(
        const u32* __restrict__ x0, const int* __restrict__ rsA, const u32* __restrict__ colA,
        u32* __restrict__ outA, int nblkA, int nA, const unsigned char* __restrict__ skipA,
        const u32* __restrict__ x1, const int* __restrict__ rsB, const u32* __restrict__ colB,
        u32* __restrict__ outB, int nblkB, int nB,
        const u16* __restrict__ px, const int* __restrict__ l0, const int* __restrict__ l1,
        const float* __restrict__ pw, int ofA, int ofB, float* __restrict__ acc, int nl,
        int npred) {
    int bid = blockIdx.x;
    int lane = threadIdx.x & 63;
    if (bid < npred) {
        int li = bid * 4 + (threadIdx.x >> 6);
        if (li >= nl) return;
        li = __builtin_amdgcn_readfirstlane(li);
        int u = l0[li], v = l1[li];
        float s = pw[ofA + lane] * h2f(px[(size_t)u * 64 + lane])
                + pw[ofB + lane] * h2f(px[(size_t)v * 64 + lane]);
#pragma unroll
        for (int off = 32; off > 0; off >>= 1) s += __shfl_xor(s, off, 64);
        if (lane == 0) acc[li] += s;
        return;
    }
    bid -= npred;
    const u32* xin; const int* rs; const u32* col; u32* out; int nlim;
    const unsigned char* skip = nullptr;
    if (bid < nblkA) { xin = x0; rs = rsA; col = colA; out = outA; nlim = nA; skip = skipA; }
    else { bid -= nblkA; xin = x1; rs = rsB; col = colB; out = outB; nlim = nB; }
    int node = bid * 16 + (threadIdx.x >> 4);   // one node per 16-lane quarter-wave
    if (node >= nlim) return;
    if (skip && !skip[node]) return;            // output never read downstream
    int fl = lane & 7;            // feature octet: features 8fl .. 8fl+7
    int g  = (lane >> 3) & 1;     // edge group 0..1 within the 16-lane group
    int beg = rs[node];
    int dgv = rs[node + 1] - beg;
    int dgm1 = dgv - 1;
    float a0 = 0.f, a1 = 0.f, a2 = 0.f, a3 = 0.f, a4 = 0.f, a5 = 0.f, a6 = 0.f, a7 = 0.f;
    uint4 p0 = make_uint4(0, 0, 0, 0), p1 = make_uint4(0, 0, 0, 0);
    uint4 p2 = make_uint4(0, 0, 0, 0), p3 = make_uint4(0, 0, 0, 0);
    const uint4* xb = (const uint4*)xin;
    const h16x2 SLO = {(_Float16)1.f, (_Float16)0.f};
    const h16x2 SHI = {(_Float16)0.f, (_Float16)1.f};
#ifdef HAVE_FDOT2
#define ACC8(P) { \
    h16x2 w0 = __builtin_bit_cast(h16x2, (P).x), w1 = __builtin_bit_cast(h16x2, (P).y); \
    h16x2 w2 = __builtin_bit_cast(h16x2, (P).z), w3 = __builtin_bit_cast(h16x2, (P).w); \
    a0 = __builtin_amdgcn_fdot2(w0, SLO, a0, false); a1 = __builtin_amdgcn_fdot2(w0, SHI, a1, false); \
    a2 = __builtin_amdgcn_fdot2(w1, SLO, a2, false); a3 = __builtin_amdgcn_fdot2(w1, SHI, a3, false); \
    a4 = __builtin_amdgcn_fdot2(w2, SLO, a4, false); a5 = __builtin_amdgcn_fdot2(w2, SHI, a5, false); \
    a6 = __builtin_amdgcn_fdot2(w3, SLO, a6, false); a7 = __builtin_amdgcn_fdot2(w3, SHI, a7, false); }
#else
#define ACC8(P) { \
    a0 += hlo((P).x); a1 += hhi((P).x); a2 += hlo((P).y); a3 += hhi((P).y); \
    a4 += hlo((P).z); a5 += hhi((P).z); a6 += hlo((P).w); a7 += hhi((P).w); }
#endif
#define SUB8(P) { \
    a0 -= hlo((P).x); a1 -= hhi((P).x); a2 -= hlo((P).y); a3 -= hhi((P).y); \
    a4 -= hlo((P).z); a5 -= hhi((P).z); a6 -= hlo((P).w); a7 -= hhi((P).w); }
    if (dgv > 0) {
        int s0 = col[beg + imin(g, dgm1)];
        int s1 = col[beg + imin(g + 2, dgm1)];
        int s2 = col[beg + imin(g + 4, dgm1)];
        int s3 = col[beg + imin(g + 6, dgm1)];
        for (int jb = 0; jb < dgv; jb += 8) {
            p0 = xb[(size_t)s0 * 8 + fl];
            p1 = xb[(size_t)s1 * 8 + fl];
            p2 = xb[(size_t)s2 * 8 + fl];
            p3 = xb[(size_t)s3 * 8 + fl];
            int nj = jb + 8 + g;
            s0 = col[beg + imin(nj, dgm1)];       // prefetch next block's cols
            s1 = col[beg + imin(nj + 2, dgm1)];
            s2 = col[beg + imin(nj + 4, dgm1)];
            s3 = col[beg + imin(nj + 6, dgm1)];
            ACC8(p0); ACC8(p1); ACC8(p2); ACC8(p3);
        }
        int jbl = (dgm1 >> 3) << 3;               // last iteration's block base
        if (jbl + g > dgm1)     SUB8(p0);
        if (jbl + 2 + g > dgm1) SUB8(p1);
        if (jbl + 4 + g > dgm1) SUB8(p2);
        if (jbl + 6 + g > dgm1) SUB8(p3);
    }
    // reduce over the 2 edge groups (lanes x ^ x+8 within each 16-lane node)
    a0 += __shfl_xor(a0, 8, 64); a1 += __shfl_xor(a1, 8, 64);
    a2 += __shfl_xor(a2, 8, 64); a3 += __shfl_xor(a3, 8, 64);
    a4 += __shfl_xor(a4, 8, 64); a5 += __shfl_xor(a5, 8, 64);
    a6 += __shfl_xor(a6, 8, 64); a7 += __shfl_xor(a7, 8, 64);
    if (g == 0) {
        float inv = __builtin_amdgcn_rcpf((float)(dgv > 1 ? dgv : 1));
        uint4 r;
        r.x = packh2(a0 * inv, a1 * inv);
        r.y = packh2(a2 * inv, a3 * inv);
        r.z = packh2(a4 * inv, a5 * inv);
        r.w = packh2(a6 * inv, a7 * inv);
        ((uint4*)out)[(size_t)node * 8 + fl] = r;
    }
#undef ACC8
#undef SUB8
}

// ---- user mix via MFMA (f16) + optional fused col_t remap blocks ----
// One wave = 16 users, K=128 (sbuf||tbuf), 64 outputs. wt=0 skips tbuf write-back
// (t-chain user rows dead, gathers redirected via remapped cols).
// First nrb blocks: col_t[i] = e<uu ? e : e+nn (runs after L1 consumed raw col_t).
__global__ __launch_bounds__(256) void mix_mfma(u16* __restrict__ sbuf, u16* __restrict__ tbuf,
        const u16* __restrict__ wb /*[64][128] f16*/, const float* __restrict__ bias, int nu,
        int wt, u32* __restrict__ colt, int ecnt, int nrb, u32 uu, u32 nn) {
    int bid = blockIdx.x;
    if (bid < nrb) {
        int idx = (bid * 256 + (int)threadIdx.x) * 4;
        if (idx + 3 < ecnt) {
            uint4 v = *(uint4*)(colt + idx);
            v.x = v.x >= uu ? v.x + nn : v.x;
            v.y = v.y >= uu ? v.y + nn : v.y;
            v.z = v.z >= uu ? v.z + nn : v.z;
            v.w = v.w >= uu ? v.w + nn : v.w;
            *(uint4*)(colt + idx) = v;
        } else {
            for (int k = idx; k < ecnt; ++k) { u32 e = colt[k]; colt[k] = e >= uu ? e + nn : e; }
        }
        return;
    }
    bid -= nrb;
    int lane = threadIdx.x & 63;
    int wv = threadIdx.x >> 6;
    int m = lane & 15, q = lane >> 4;
    int ubase = bid * 64 + wv * 16;
    int ul = ubase + m;
    int usafe = ul < nu ? ul : nu - 1;
    const f16x8* srow = (const f16x8*)(sbuf + (size_t)usafe * 64);
    const f16x8* trow = (const f16x8*)(tbuf + (size_t)usafe * 64);
    f16x8 a0 = srow[q];
    f16x8 a1 = srow[4 + q];
    f16x8 a2 = trow[q];
    f16x8 a3 = trow[4 + q];
    f32x4 accv[4];
#pragma unroll
    for (int t = 0; t < 4; ++t) { accv[t].x = accv[t].y = accv[t].z = accv[t].w = 0.f; }
#pragma unroll
    for (int t = 0; t < 4; ++t) {
        const u16* wd = wb + (size_t)(t * 16 + m) * 128;
        accv[t] = __builtin_amdgcn_mfma_f32_16x16x32_f16(a0, *(const f16x8*)(wd + q * 8), accv[t], 0, 0, 0);
        accv[t] = __builtin_amdgcn_mfma_f32_16x16x32_f16(a1, *(const f16x8*)(wd + 32 + q * 8), accv[t], 0, 0, 0);
        accv[t] = __builtin_amdgcn_mfma_f32_16x16x32_f16(a2, *(const f16x8*)(wd + 64 + q * 8), accv[t], 0, 0, 0);
        accv[t] = __builtin_amdgcn_mfma_f32_16x16x32_f16(a3, *(const f16x8*)(wd + 96 + q * 8), accv[t], 0, 0, 0);
    }
    int urow = ubase + q * 4;
#pragma unroll
    for (int t = 0; t < 4; ++t) {
        float bv = bias[t * 16 + m];
#pragma unroll
        for (int r = 0; r < 4; ++r) {
            int uu2 = urow + r;
            if (uu2 < nu) {
                u16 h = f2h(accv[t][r] + bv);
                sbuf[(size_t)uu2 * 64 + t * 16 + m] = h;
                if (wt) tbuf[(size_t)uu2 * 64 + t * 16 + m] = h;
            }
        }
    }
}

// ---- standalone final predictor ----
__global__ __launch_bounds__(256) void predl_kernel(const u16* __restrict__ xb,
        const int* __restrict__ l0, const int* __restrict__ l1,
        const float* __restrict__ pw, int ofA, int ofB,
        float* __restrict__ acc, int nl,
        const float* __restrict__ pb, float* __restrict__ out) {
    int li = blockIdx.x * 4 + (threadIdx.x >> 6);
    if (li >= nl) return;
    li = __builtin_amdgcn_readfirstlane(li);
    int lane = threadIdx.x & 63;
    int u = l0[li], v = l1[li];
    float s = pw[ofA + lane] * h2f(xb[(size_t)u * 64 + lane])
            + pw[ofB + lane] * h2f(xb[(size_t)v * 64 + lane]);
#pragma unroll
    for (int off = 32; off > 0; off >>= 1) s += __shfl_xor(s, off, 64);
    if (lane == 0) {
        float t = acc[li] + s + pb[0];
        t = t > 0.f ? t : 0.01f * t;
        out[li] = 1.f / (1.f + expf(-t));
    }
}

extern "C" void kernel_launch(void* const* d_in, const int* in_sizes, int n_in,
                              void* d_out, int out_size, void* d_ws, size_t ws_size,
                              hipStream_t stream) {
    const int*   se  = (const int*)d_in[0];   // [2,E] src then dst
    const int*   te  = (const int*)d_in[1];
    const int*   lk  = (const int*)d_in[2];   // [2,NLINK]
    const float* emb = (const float*)d_in[3]; // [N,64]
    const float* mw  = (const float*)d_in[4]; // [3,64,128]
    const float* mb  = (const float*)d_in[5]; // [3,64]
    const float* pw  = (const float*)d_in[6]; // [1,512]
    const float* pb  = (const float*)d_in[7]; // [1]
    float* out = (float*)d_out;

    const int E  = in_sizes[0] / 2;
    const int NL = in_sizes[2] / 2;
    const int N  = in_sizes[3] / 64;
    const int U  = 100000;
    const int NB = (N + NODESB - 1) >> BSHIFT;   // 782 coarse buckets

    char* p = (char*)d_ws;
    auto alloc = [&](size_t bytes) -> char* {
        char* r = p;
        p += (bytes + 255) & ~(size_t)255;
        return r;
    };
    const size_t bufb = (size_t)N * 128;                    // one node buffer, bytes
    const bool contig = (bufb % 256) == 0;                  // pair layout needs no pad
    auto rnd = [](size_t b) { return (b + 255) & ~(size_t)255; };
    size_t wide_total = 4 * rnd(bufb) + 2 * rnd((size_t)E * 4) + 2 * rnd((size_t)(N + 1) * 4)
                      + rnd((size_t)NL * 4) + rnd(2 * NBPAD * 4) + 2 * rnd((NBPAD + 1) * 4)
                      + rnd(2 * NBPAD * 4) + rnd(3 * 64 * 128 * 2) + rnd((size_t)N);
    bool wide = contig && (wide_total <= ws_size);

    u32 *A, *B, *C, *Dd = nullptr;
    if (wide) {
        A  = (u32*)alloc(bufb);   // pair P1 = [A | B]   (s-chain | t-chain)
        B  = (u32*)alloc(bufb);
        C  = (u32*)alloc(bufb);   // pair P2 = [C | Dd]
        Dd = (u32*)alloc(bufb);
    } else {
        A  = (u32*)alloc(bufb);
        B  = (u32*)alloc(bufb);
        C  = (u32*)alloc(bufb);
    }
    u32* col_s = (u32*)alloc((size_t)E * 4);
    u32* col_t = (u32*)alloc((size_t)E * 4);
    int* rs_s  = (int*)alloc((size_t)(N + 1) * 4);
    int* rs_t  = (int*)alloc((size_t)(N + 1) * 4);
    float* acc = (float*)alloc((size_t)NL * 4);
    int* gcnt2 = (int*)alloc(2 * NBPAD * 4);
    int* bbase_s = (int*)alloc((NBPAD + 1) * 4);
    int* bbase_t = (int*)alloc((NBPAD + 1) * 4);
    int* cur2  = (int*)alloc(2 * NBPAD * 4);
    u16* mwb   = (u16*)alloc(3 * 64 * 128 * 2);
    unsigned char* flags = (unsigned char*)alloc((size_t)N);

    hipMemsetAsync(gcnt2, 0, 2 * NBPAD * 4, stream);
    hipMemsetAsync(flags, 0, (size_t)N, stream);

    const int NHIST = (E + HCHUNK - 1) / HCHUNK;     // 367
    const int NBIN  = (E + BCHUNK - 1) / BCHUNK;     // 367
    const int NWPREP = 96;
    const int NCONV = (N * 64 + 1023) / 1024;        // 12500
    const int GA    = (N + 15) / 16;                 // 12500 agg blocks (16 nodes/block)
    const int GAU   = (U + 15) / 16;                 // 6250 (layer-3 t-agg: users only)
    const int GP    = (NL + 3) / 4;                  // 25000
    const int GM    = (U + 63) / 64;                 // 1563
    const int NRB   = (E + 1023) / 1024;             // 2930 remap blocks (4 entries/thread)

    // D1: hist both + W prep + emb->f16 into C (P2 lower)
    prep_hist<<<2 * NHIST + NWPREP + NCONV, 256, 0, stream>>>(
        se + E, te + E, E, gcnt2, mw, mwb, emb, C, N * 64, NHIST, NWPREP);
    // D2: parallel bucket scans + pred0 + link flags
    scan_pred0<<<2 + GP, 256, 0, stream>>>(gcnt2, NB, bbase_s, bbase_t, cur2, rs_s, rs_t,
                                           N, emb, lk, lk + NL, pw, acc, NL, flags);
    // D3: bin both (LDS presort)
    bin3_kernel<<<2 * NBIN, 256, 0, stream>>>(se, se + E, te, te + E, E, cur2, col_s, col_t, NBIN);
    // D4: sort both
    sort2_kernel<<<2 * NB, 256, 0, stream>>>(col_s, col_t, bbase_s, bbase_t, rs_s, rs_t, N, NB);

    if (wide) {
        // L1 merged: both lists gather C (full sharing, unmapped cols) -> A (s1), B (t1)
        aggp_kernel<<<2 * GA, 256, 0, stream>>>(
            C, rs_s, col_s, A, GA, N, nullptr,  C, rs_t, col_t, B, GA, N,
            (const u16*)nullptr, nullptr, nullptr, nullptr, 0, 0, nullptr, 0, 0);
        // mix1 (write A users only) + col_t remap (src<U ? src : src+N)
        mix_mfma<<<GM + NRB, 256, 0, stream>>>((u16*)A, (u16*)B, mwb + 0 * 8192, mb + 0 * 64,
                                               U, 0, col_t, E, NRB, (u32)U, (u32)N);
        // L2 merged + pred1(A): s: base A, col_s -> C ; t: base A (remapped col_t spans A|B) -> Dd
        aggp_kernel<<<GP + 2 * GA, 256, 0, stream>>>(
            A, rs_s, col_s, C, GA, N, nullptr,  A, rs_t, col_t, Dd, GA, N,
            (const u16*)A, lk, lk + NL, pw, 64, 320, acc, NL, GP);
        // mix2 (write C users only)
        mix_mfma<<<GM, 256, 0, stream>>>((u16*)C, (u16*)Dd, mwb + 1 * 8192, mb + 1 * 64,
                                         U, 0, nullptr, 0, 0, 0, 0);
        // L3 merged + pred2(C): s: base C, col_s -> A (link-flagged nodes only) ;
        //                       t: base C (remapped col_t spans C|Dd) -> B (users only)
        aggp_kernel<<<GP + GA + GAU, 256, 0, stream>>>(
            C, rs_s, col_s, A, GA, N, flags,  C, rs_t, col_t, B, GAU, U,
            (const u16*)C, lk, lk + NL, pw, 128, 384, acc, NL, GP);
        // mix3 (write A users only; unflagged users compute garbage, never read)
        mix_mfma<<<GM, 256, 0, stream>>>((u16*)A, (u16*)B, mwb + 2 * 8192, mb + 2 * 64,
                                         U, 0, nullptr, 0, 0, 0, 0);
        // final predictor on A (s-chain L3 mixed)
        predl_kernel<<<GP, 256, 0, stream>>>((const u16*)A, lk, lk + NL, pw, 192, 448, acc, NL, pb, out);
    } else {
        // ---- fallback: 3-buffer sequential schedule, unmapped cols ----
        aggp_kernel<<<2 * GA, 256, 0, stream>>>(
            C, rs_s, col_s, A, GA, N, nullptr,  C, rs_t, col_t, B, GA, N,
            (const u16*)nullptr, nullptr, nullptr, nullptr, 0, 0, nullptr, 0, 0);
        mix_mfma<<<GM, 256, 0, stream>>>((u16*)A, (u16*)B, mwb + 0 * 8192, mb + 0 * 64,
                                         U, 1, nullptr, 0, 0, 0, 0);
        aggp_kernel<<<GP + GA, 256, 0, stream>>>(
            A, rs_s, col_s, C, GA, N, nullptr,
            nullptr, nullptr, nullptr, nullptr, 0, 0,
            (const u16*)A, lk, lk + NL, pw, 64, 320, acc, NL, GP);
        aggp_kernel<<<GA, 256, 0, stream>>>(
            B, rs_t, col_t, A, GA, N, nullptr,
            nullptr, nullptr, nullptr, nullptr, 0, 0,
            (const u16*)nullptr, nullptr, nullptr, nullptr, 0, 0, nullptr, 0, 0);
        mix_mfma<<<GM, 256, 0, stream>>>((u16*)C, (u16*)A, mwb + 1 * 8192, mb + 1 * 64,
                                         U, 1, nullptr, 0, 0, 0, 0);
        aggp_kernel<<<GP + GA, 256, 0, stream>>>(
            C, rs_s, col_s, B, GA, N, nullptr,
            nullptr, nullptr, nullptr, nullptr, 0, 0,
            (const u16*)C, lk, lk + NL, pw, 128, 384, acc, NL, GP);
        aggp_kernel<<<GAU, 256, 0, stream>>>(
            A, rs_t, col_t, C, GAU, U, nullptr,
            nullptr, nullptr, nullptr, nullptr, 0, 0,
            (const u16*)nullptr, nullptr, nullptr, nullptr, 0, 0, nullptr, 0, 0);
        mix_mfma<<<GM, 256, 0, stream>>>((u16*)B, (u16*)C, mwb + 2 * 8192, mb + 2 * 64,
                                         U, 1, nullptr, 0, 0, 0, 0);
        predl_kernel<<<GP, 256, 0, stream>>>((const u16*)B, lk, lk + NL, pw, 192, 448, acc, NL, pb, out);
    }
}